// Round 1
// baseline (2196.507 us; speedup 1.0000x reference)
//
#include <hip/hip_runtime.h>

// Segment-sum: out[v, :] = sum over n with X_node[n]==v of H[n, :]
// N = 2,000,000 rows, D = 64, V = 100,000 buckets. fp32 in/out.
//
// Round 0: atomic scatter. 16 threads per row, float4 load per thread
// (16 B/lane coalesced), 4 atomicAdds to consecutive addresses.
// Output zeroed via hipMemsetAsync (graph-capture safe).

constexpr int D = 64;

__global__ __launch_bounds__(256) void AggrSum_scatter_kernel(
    const float4* __restrict__ H4,   // H viewed as [N, 16] float4
    const int* __restrict__ idx,     // X_node as int32
    float* __restrict__ out,         // [V, 64]
    int n_rows)
{
    long long t = (long long)blockIdx.x * blockDim.x + threadIdx.x;
    int n = (int)(t >> 4);           // row index
    int q = (int)(t & 15);           // float4 slot within the row
    if (n >= n_rows) return;

    int node = idx[n];
    float4 v = H4[(size_t)n * 16 + q];

    float* o = out + (size_t)node * D + q * 4;
    atomicAdd(o + 0, v.x);
    atomicAdd(o + 1, v.y);
    atomicAdd(o + 2, v.z);
    atomicAdd(o + 3, v.w);
}

extern "C" void kernel_launch(void* const* d_in, const int* in_sizes, int n_in,
                              void* d_out, int out_size, void* d_ws, size_t ws_size,
                              hipStream_t stream) {
    const float* H  = (const float*)d_in[0];
    const int* idx  = (const int*)d_in[1];
    float* out      = (float*)d_out;
    int n_rows      = in_sizes[1];   // N = 2,000,000

    // Harness re-poisons d_out to 0xAA before every timed launch — zero it.
    hipMemsetAsync(d_out, 0, (size_t)out_size * sizeof(float), stream);

    long long total_threads = (long long)n_rows * 16;
    int block = 256;
    int grid = (int)((total_threads + block - 1) / block);
    AggrSum_scatter_kernel<<<grid, block, 0, stream>>>(
        (const float4*)H, idx, out, n_rows);
}

// Round 2
// 929.968 us; speedup vs baseline: 2.3619x; 2.3619x over previous
//
#include <hip/hip_runtime.h>

// Segment-sum: out[v,:] = sum_{n: X_node[n]==v} H[n,:]
// N=2M rows, D=64, V=100k. fp32.
//
// Round 1 showed atomic scatter is write-amplification bound: 128M fp32
// atomics x 16B write-through = 2.05 GB HBM writes for a 25.6 MB output.
// Round 2: counting sort by node id + atomic-free gather-reduce.
//   K1 hist -> K2/K3/K4 exclusive scan -> K5 scatter perm -> K6 gather.
// K6: one wave per node, lane=feature -> each H row is ONE coalesced 256B
// read, accumulated in registers, one coalesced 256B store. No atomics.

constexpr int D = 64;
constexpr int SCAN_TILE = 1024;

__global__ void hist_kernel(const int* __restrict__ idx, int* __restrict__ hist, int N) {
    int stride = gridDim.x * blockDim.x;
    for (int n = blockIdx.x * blockDim.x + threadIdx.x; n < N; n += stride)
        atomicAdd(&hist[idx[n]], 1);
}

__global__ __launch_bounds__(1024) void scan_tile_kernel(
    const int* __restrict__ hist, int* __restrict__ starts,
    int* __restrict__ tile_sums, int V)
{
    __shared__ int tmp[SCAN_TILE];
    int t = threadIdx.x;
    int v = blockIdx.x * SCAN_TILE + t;
    int x = (v < V) ? hist[v] : 0;
    tmp[t] = x;
    __syncthreads();
    // Hillis-Steele inclusive scan (double-barrier, in-place safe)
    for (int off = 1; off < SCAN_TILE; off <<= 1) {
        int y = (t >= off) ? tmp[t - off] : 0;
        __syncthreads();
        tmp[t] += y;
        __syncthreads();
    }
    if (v < V) starts[v] = tmp[t] - x;          // exclusive within tile
    if (t == SCAN_TILE - 1) tile_sums[blockIdx.x] = tmp[t];
}

__global__ void scan_sums_kernel(int* tile_sums, int n_tiles) {
    if (threadIdx.x == 0 && blockIdx.x == 0) {
        int run = 0;
        for (int i = 0; i < n_tiles; ++i) { int s = tile_sums[i]; tile_sums[i] = run; run += s; }
    }
}

__global__ __launch_bounds__(1024) void scan_add_kernel(
    int* __restrict__ starts, const int* __restrict__ tile_sums, int V)
{
    int v = blockIdx.x * SCAN_TILE + threadIdx.x;
    if (v < V) starts[v] += tile_sums[blockIdx.x];
}

__global__ void scatter_kernel(const int* __restrict__ idx, int* __restrict__ cursor,
                               int* __restrict__ perm, int N)
{
    int stride = gridDim.x * blockDim.x;
    for (int n = blockIdx.x * blockDim.x + threadIdx.x; n < N; n += stride) {
        int node = idx[n];
        int pos = atomicAdd(&cursor[node], 1);
        perm[pos] = n;
    }
}

// One wave per node. Lane d accumulates feature d. perm entries loaded
// cooperatively (64/wave, coalesced) then broadcast via shfl.
__global__ __launch_bounds__(256) void gather_kernel(
    const float* __restrict__ H, const int* __restrict__ perm,
    const int* __restrict__ starts, float* __restrict__ out, int V, int N)
{
    int wid  = blockIdx.x * (blockDim.x >> 6) + (threadIdx.x >> 6);
    int lane = threadIdx.x & 63;
    if (wid >= V) return;

    int beg = starts[wid];
    int end = (wid + 1 < V) ? starts[wid + 1] : N;
    int cnt = end - beg;

    float acc = 0.f;
    int base = 0;
    while (base < cnt) {
        int m = cnt - base; if (m > 64) m = 64;
        int n_l = (lane < m) ? perm[beg + base + lane] : 0;
        int i = 0;
        for (; i + 3 < m; i += 4) {
            int n0 = __shfl(n_l, i);
            int n1 = __shfl(n_l, i + 1);
            int n2 = __shfl(n_l, i + 2);
            int n3 = __shfl(n_l, i + 3);
            float a0 = H[(size_t)n0 * D + lane];
            float a1 = H[(size_t)n1 * D + lane];
            float a2 = H[(size_t)n2 * D + lane];
            float a3 = H[(size_t)n3 * D + lane];
            acc += a0; acc += a1; acc += a2; acc += a3;
        }
        for (; i < m; ++i) {
            int n = __shfl(n_l, i);
            acc += H[(size_t)n * D + lane];
        }
        base += m;
    }
    out[(size_t)wid * D + lane] = acc;
}

// ---- round-0 fallback (only if ws too small) ----
__global__ __launch_bounds__(256) void scatter_atomic_kernel(
    const float4* __restrict__ H4, const int* __restrict__ idx,
    float* __restrict__ out, int n_rows)
{
    long long t = (long long)blockIdx.x * blockDim.x + threadIdx.x;
    int n = (int)(t >> 4), q = (int)(t & 15);
    if (n >= n_rows) return;
    int node = idx[n];
    float4 v = H4[(size_t)n * 16 + q];
    float* o = out + (size_t)node * D + q * 4;
    atomicAdd(o + 0, v.x); atomicAdd(o + 1, v.y);
    atomicAdd(o + 2, v.z); atomicAdd(o + 3, v.w);
}

static inline size_t align_up(size_t x, size_t a) { return (x + a - 1) & ~(a - 1); }

extern "C" void kernel_launch(void* const* d_in, const int* in_sizes, int n_in,
                              void* d_out, int out_size, void* d_ws, size_t ws_size,
                              hipStream_t stream) {
    const float* H = (const float*)d_in[0];
    const int* idx = (const int*)d_in[1];
    float* out     = (float*)d_out;
    int N = in_sizes[1];
    int V = out_size / D;
    int n_tiles = (V + SCAN_TILE - 1) / SCAN_TILE;

    // workspace layout
    size_t off_perm  = 0;
    size_t off_hist  = align_up(off_perm + (size_t)N * 4, 256);
    size_t off_start = align_up(off_hist + (size_t)V * 4, 256);
    size_t off_cur   = align_up(off_start + (size_t)V * 4, 256);
    size_t off_tsum  = align_up(off_cur + (size_t)V * 4, 256);
    size_t need      = off_tsum + (size_t)n_tiles * 4;

    if (ws_size < need) {
        // fallback: round-0 atomic scatter
        hipMemsetAsync(d_out, 0, (size_t)out_size * sizeof(float), stream);
        long long total = (long long)N * 16;
        scatter_atomic_kernel<<<(int)((total + 255) / 256), 256, 0, stream>>>(
            (const float4*)H, idx, out, N);
        return;
    }

    char* ws = (char*)d_ws;
    int* perm      = (int*)(ws + off_perm);
    int* hist      = (int*)(ws + off_hist);
    int* starts    = (int*)(ws + off_start);
    int* cursor    = (int*)(ws + off_cur);
    int* tile_sums = (int*)(ws + off_tsum);

    hipMemsetAsync(hist, 0, (size_t)V * 4, stream);

    hist_kernel<<<(N + 255) / 256, 256, 0, stream>>>(idx, hist, N);
    scan_tile_kernel<<<n_tiles, SCAN_TILE, 0, stream>>>(hist, starts, tile_sums, V);
    scan_sums_kernel<<<1, 64, 0, stream>>>(tile_sums, n_tiles);
    scan_add_kernel<<<n_tiles, SCAN_TILE, 0, stream>>>(starts, tile_sums, V);
    hipMemcpyAsync(cursor, starts, (size_t)V * 4, hipMemcpyDeviceToDevice, stream);
    scatter_kernel<<<(N + 255) / 256, 256, 0, stream>>>(idx, cursor, perm, N);

    int waves_per_block = 256 / 64;
    int grid = (V + waves_per_block - 1) / waves_per_block;
    gather_kernel<<<grid, 256, 0, stream>>>(H, perm, starts, out, V, N);
}